// Round 13
// baseline (319.282 us; speedup 1.0000x reference)
//
#include <hip/hip_runtime.h>

// Problem constants: B=4, h=w=z=16 -> N=4096, C=128, Cq=16
#define NB     4
#define NN     4096
#define NC     128
#define NCQ    16
#define NROWS  (NB * NN)      // 16384
#define NSLICE 4
#define NIT    (NN / 64 / NSLICE)   // 16 iterations of 64 keys per slice

typedef __attribute__((ext_vector_type(8)))  __bf16 bf16x8;
typedef __attribute__((ext_vector_type(4)))  float  f32x4;
typedef __attribute__((ext_vector_type(16))) float  f32x16;

#define MFMA16(a,b,c) __builtin_amdgcn_mfma_f32_16x16x32_bf16((a),(b),(c),0,0,0)
#define MFMA32(a,b,c) __builtin_amdgcn_mfma_f32_32x32x16_bf16((a),(b),(c),0,0,0)
#define LOG2E 1.44269504f
// Schraudolph bias for direct-to-bf16 exp2: bits(bf16(2^s)) ~= 128*s + 16248.66
#define SCH_BIAS 16248.66f

__device__ __forceinline__ f32x16 zero16() {
    f32x16 v;
    #pragma unroll
    for (int i = 0; i < 16; ++i) v[i] = 0.f;
    return v;
}

// Swizzled fragment layouts (lane = lh*32 + l31):
//  qswz: [batch][qb32][lane][8]  elem j = (LOG2E * Q)[32*qb32 + l31][ch = 8*lh + j]
//  kswz: [batch][kb32][lane][8]  elem j = K[32*kb32 + l31][ch = 8*lh + j]
//  vswz: [batch][kb16][cg][lane][8]
//        elem j = V^T[ch = 32*cg + l31][key = 16*kb16 + 4*lh + (j&3) + 8*(j>>2)]

// ---------------------------------------------------------------------------
// Kernel 1: projections via MFMA (R12 structure) with W^T staged in-block
// directly from fp32 Wb/Wc/Wd (wtrans kernel folded in). Also zeroes the
// combine counter cnt[bid] for kernel 2's last-finisher reduction.
// ---------------------------------------------------------------------------
__global__ __launch_bounds__(256) void proj_kernel(
    const float* __restrict__ x,  const float* __restrict__ Wb,
    const float* __restrict__ Wc, const float* __restrict__ Wd,
    __bf16* __restrict__ qswz, __bf16* __restrict__ kswz,
    __bf16* __restrict__ vswz, int* __restrict__ cnt)
{
    __shared__ __align__(16) __bf16 xsh[32 * 136];   // [row][136]
    __shared__ __align__(16) __bf16 wt [160 * 136];  // [outcol][136]
    __shared__ __align__(16) float  osb[4][16 * 17]; // per-wave transpose buffer

    const int  t    = threadIdx.x;
    const int  lane = t & 63, w = t >> 6;
    const int  q16  = lane & 15, quad = lane >> 4;
    const long row0 = (long)blockIdx.x * 32;
    const int  batch = (int)(row0 >> 12);
    const int  nloc  = (int)(row0 & 4095);
    const int  rh   = w & 1;
    const int  og   = (w >> 1) * 5;

    if (t == 0) cnt[blockIdx.x] = 0;     // combine counter for attn kernel

    // ---- stage X tile (fp32 -> bf16), [32][128] -> xsh stride 136 ----
    #pragma unroll
    for (int i = 0; i < 4; ++i) {
        int idx = t + 256 * i;           // < 1024
        int r = idx >> 5, c4 = (idx & 31) * 4;
        float4 xv = *(const float4*)&x[(row0 + r) * NC + c4];
        union { __bf16 h[4]; uint2 u; } cv;
        cv.h[0] = (__bf16)xv.x; cv.h[1] = (__bf16)xv.y;
        cv.h[2] = (__bf16)xv.z; cv.h[3] = (__bf16)xv.w;
        *(uint2*)&xsh[r * 136 + c4] = cv.u;
    }
    // ---- stage W^T from fp32 globals: wt[oc][ch], oc: 0..15 Wb, 16..31 Wc,
    //      32..159 Wd. Coalesced float4 reads, LDS-transposed scalar writes.
    #pragma unroll
    for (int i = 0; i < 2; ++i) {        // Wb: 512 float4
        int idx = t + 256 * i;
        int ch = idx >> 2, o4 = (idx & 3) * 4;
        float4 v = *(const float4*)&Wb[ch * 16 + o4];
        wt[(o4 + 0) * 136 + ch] = (__bf16)v.x;
        wt[(o4 + 1) * 136 + ch] = (__bf16)v.y;
        wt[(o4 + 2) * 136 + ch] = (__bf16)v.z;
        wt[(o4 + 3) * 136 + ch] = (__bf16)v.w;
    }
    #pragma unroll
    for (int i = 0; i < 2; ++i) {        // Wc: 512 float4 -> oc 16..31
        int idx = t + 256 * i;
        int ch = idx >> 2, o4 = (idx & 3) * 4;
        float4 v = *(const float4*)&Wc[ch * 16 + o4];
        wt[(16 + o4 + 0) * 136 + ch] = (__bf16)v.x;
        wt[(16 + o4 + 1) * 136 + ch] = (__bf16)v.y;
        wt[(16 + o4 + 2) * 136 + ch] = (__bf16)v.z;
        wt[(16 + o4 + 3) * 136 + ch] = (__bf16)v.w;
    }
    #pragma unroll
    for (int i = 0; i < 16; ++i) {       // Wd: 4096 float4 -> oc 32..159
        int idx = t + 256 * i;
        int ch = idx >> 5, o4 = (idx & 31) * 4;
        float4 v = *(const float4*)&Wd[ch * 128 + o4];
        wt[(32 + o4 + 0) * 136 + ch] = (__bf16)v.x;
        wt[(32 + o4 + 1) * 136 + ch] = (__bf16)v.y;
        wt[(32 + o4 + 2) * 136 + ch] = (__bf16)v.z;
        wt[(32 + o4 + 3) * 136 + ch] = (__bf16)v.w;
    }
    __syncthreads();

    bf16x8 xf[4];
    #pragma unroll
    for (int kc = 0; kc < 4; ++kc)
        xf[kc] = *(const bf16x8*)&xsh[(rh * 16 + q16) * 136 + kc * 32 + quad * 8];

    float* osw = osb[w];
    #pragma unroll
    for (int oc_t = 0; oc_t < 5; ++oc_t) {
        const int oset = og + oc_t;
        f32x4 acc = {0.f, 0.f, 0.f, 0.f};
        #pragma unroll
        for (int kc = 0; kc < 4; ++kc) {
            bf16x8 wf = *(const bf16x8*)&wt[(oset * 16 + q16) * 136 + kc * 32 + quad * 8];
            acc = MFMA16(wf, xf[kc], acc);   // D'[oc][row]
        }
        #pragma unroll
        for (int r = 0; r < 4; ++r)
            osw[(quad * 4 + r) * 17 + q16] = acc[r];   // osb[oc16][xrow16]

        if (oset >= 2) {
            int ch_l = lane & 15, lh_t = (lane >> 4) & 1, jh = lane >> 5;
            union { __bf16 h[4]; uint2 u; } cv;
            #pragma unroll
            for (int u2 = 0; u2 < 4; ++u2)
                cv.h[u2] = (__bf16)osw[ch_l * 17 + 8 * jh + 4 * lh_t + u2];
            int kb16 = (nloc >> 4) + rh;
            int cg   = (oset - 2) >> 1;
            int l31v = ((oset - 2) & 1) * 16 + ch_l;
            size_t off = ((((size_t)batch * 256 + kb16) * 4 + cg) << 9)
                       + (size_t)(lh_t * 32 + l31v) * 8 + jh * 4;
            *(uint2*)&vswz[off] = cv.u;
        } else if (lane < 32) {
            int xr = lane & 15, lh_t = lane >> 4;
            const float qsc = (oset == 0) ? LOG2E : 1.f;  // fold log2e into Q
            union { __bf16 h[8]; uint4 u; } cv;
            #pragma unroll
            for (int j = 0; j < 8; ++j)
                cv.h[j] = (__bf16)(osw[(8 * lh_t + j) * 17 + xr] * qsc);
            size_t off = ((((size_t)batch * 128 + (nloc >> 5)) * 64)
                       + (size_t)(lh_t * 32 + rh * 16 + xr)) * 8;
            __bf16* dst = (oset == 0) ? qswz : kswz;
            *(uint4*)&dst[off] = cv.u;
        }
    }
}

// ---------------------------------------------------------------------------
// Kernel 2: flash attention (R12 core, frozen) + fused combine epilogue.
// The 2 sibling blocks per (batch,qb32) (sp=0/1 -> different XCDs) rendezvous
// on cnt[]: release fence + atomicAdd; the second finisher acquires and does
// the 32-row combine (sum 4 slice partials, gamma*(O/l)+x) inline.
// ---------------------------------------------------------------------------
__global__ __launch_bounds__(256, 3) void attn_kernel(
    const __bf16* __restrict__ qswz, const __bf16* __restrict__ kswz,
    const __bf16* __restrict__ vswz, __bf16* __restrict__ Opart,
    float* __restrict__ lws, int* __restrict__ cnt,
    const float* __restrict__ x, const float* __restrict__ gamma,
    float* __restrict__ out)
{
    const int t    = threadIdx.x;
    const int lane = t & 63, w = t >> 6;
    const int l31 = lane & 31, lh = lane >> 5;
    const int bid   = blockIdx.x;
    const int xcd   = bid & 7;
    const int batch = xcd >> 1;              // constant per XCD
    const int sp    = xcd & 1;               // slice-pair, constant per XCD
    const int qb32  = bid >> 3;              // 0..127
    const int h     = w & 1;                 // channel half
    const int slice = sp * 2 + (w >> 1);     // 0..3
    const int ks0   = slice * (64 * NIT);

    // Q B-frag, fixed: n = q = 32*qb32 + l31, k = ch = 8*lh + j
    const bf16x8 qf = *(const bf16x8*)
        &qswz[(((size_t)batch * 128 + qb32) * 64 + lane) * 8];

    const __bf16* kptr = kswz + ((size_t)batch * 128 + (ks0 >> 5)) * 512 + lane * 8;
    const __bf16* vptr = vswz + ((size_t)batch * 256 + (ks0 >> 4)) * 2048
                       + h * 1024 + lane * 8;

    // ones B-fragment (bf16 1.0 pairs) for the l-summing MFMA
    union { uint32_t u[4]; bf16x8 f; } onesu;
    #pragma unroll
    for (int i = 0; i < 4; ++i) onesu.u[i] = 0x3F803F80u;
    const bf16x8 ones = onesu.f;

    f32x16 O0 = zero16(), O1 = zero16(), Ol = zero16();

    bf16x8 kf0 = *(const bf16x8*)(kptr);
    bf16x8 kf1 = *(const bf16x8*)(kptr + 512);
    bf16x8 va[8], vb[8];
    #pragma unroll
    for (int b = 0; b < 4; ++b) {           // iter-0 V frags (ct = 0,1)
        va[2*b]     = *(const bf16x8*)(vptr + (size_t)(b * 4)     * 512);
        va[2*b + 1] = *(const bf16x8*)(vptr + (size_t)(b * 4 + 1) * 512);
    }
    f32x16 S0 = MFMA32(kf0, qf, zero16());
    f32x16 S1 = MFMA32(kf1, qf, zero16());

#define ATTN_BODY(IT, CUR, NXT)                                               \
    {                                                                         \
        const int itn = ((IT) + 1 < NIT) ? (IT) + 1 : (IT);                   \
        kf0 = *(const bf16x8*)(kptr + (size_t)itn * 1024);                    \
        kf1 = *(const bf16x8*)(kptr + (size_t)itn * 1024 + 512);              \
        _Pragma("unroll")                                                     \
        for (int b = 0; b < 4; ++b) {                                         \
            NXT[2*b]     = *(const bf16x8*)(vptr + (size_t)((itn*4+b)*4)*512);\
            NXT[2*b + 1] = *(const bf16x8*)(vptr + (size_t)((itn*4+b)*4+1)*512);\
        }                                                                     \
        union { uint32_t u32[16]; bf16x8 f[4]; } pk;                          \
        _Pragma("unroll")                                                     \
        for (int i = 0; i < 8; ++i) {                                         \
            int e0 = (int)fmaf(S0[2*i],   128.f, SCH_BIAS);                   \
            int e1 = (int)fmaf(S0[2*i+1], 128.f, SCH_BIAS);                   \
            int e2 = (int)fmaf(S1[2*i],   128.f, SCH_BIAS);                   \
            int e3 = (int)fmaf(S1[2*i+1], 128.f, SCH_BIAS);                   \
            pk.u32[i]     = (uint32_t)((e1 << 16) | e0);                      \
            pk.u32[8 + i] = (uint32_t)((e3 << 16) | e2);                      \
        }                                                                     \
        _Pragma("unroll")                                                     \
        for (int b = 0; b < 4; ++b) {                                         \
            O0 = MFMA32(pk.f[b], CUR[2*b],     O0);                           \
            O1 = MFMA32(pk.f[b], CUR[2*b + 1], O1);                           \
            Ol = MFMA32(pk.f[b], ones,         Ol);                           \
        }                                                                     \
        S0 = MFMA32(kf0, qf, zero16());                                       \
        S1 = MFMA32(kf1, qf, zero16());                                       \
    }

    for (int it = 0; it < NIT; it += 2) {
        ATTN_BODY(it,     va, vb);
        ATTN_BODY(it + 1, vb, va);
    }
#undef ATTN_BODY

    const long base = (long)batch * NN;

    // ---- l: Ol reg r holds sum over ALL this slice's keys for q(r), any col.
    if (h == 0 && l31 == 0) {
        #pragma unroll
        for (int r = 0; r < 16; ++r) {
            int q = qb32 * 32 + (r & 3) + 8 * (r >> 2) + 4 * lh;
            lws[(size_t)slice * NROWS + base + q] = Ol[r];
        }
    }

    // ---- O partial -> Opart[slice][row][ch] bf16 (col = ch = 64h+32ct+l31) --
    #pragma unroll
    for (int ct = 0; ct < 2; ++ct) {
        f32x16 Ov = ct ? O1 : O0;
        #pragma unroll
        for (int r = 0; r < 16; ++r) {
            int q = qb32 * 32 + (r & 3) + 8 * (r >> 2) + 4 * lh;
            Opart[((size_t)slice * NROWS + base + q) * NC + 64 * h + 32 * ct + l31]
                = (__bf16)Ov[r];
        }
    }

    // ---- fused combine: last-arriving sibling block reduces 32 rows ----
    __shared__ float gl[32];
    __shared__ int doneSh;
    __syncthreads();                     // all waves' stores drained (vmcnt 0)
    __threadfence();                     // release: L2 writeback, device scope
    if (t == 0)
        doneSh = atomicAdd(&cnt[batch * 128 + qb32], 1);
    __syncthreads();
    if (doneSh == 1) {
        __threadfence();                 // acquire: invalidate stale caches
        const long r0g = base + qb32 * 32;
        if (t < 32) {
            float l = 0.f;
            #pragma unroll
            for (int s = 0; s < NSLICE; ++s)
                l += lws[(size_t)s * NROWS + r0g + t];
            gl[t] = gamma[0] / l;
        }
        __syncthreads();
        const size_t s1 = (size_t)NROWS * NC;
        #pragma unroll
        for (int i = 0; i < 4; ++i) {
            int idx2 = t + 256 * i;            // < 1024 float4 groups
            int r = idx2 >> 5, c4 = (idx2 & 31) * 4;
            size_t g = (size_t)(r0g + r) * NC + c4;
            float a0 = 0.f, a1 = 0.f, a2 = 0.f, a3 = 0.f;
            #pragma unroll
            for (int s = 0; s < NSLICE; ++s) {
                union { __bf16 hh[4]; uint2 u; } a;
                a.u = *(const uint2*)&Opart[s1 * s + g];
                a0 += (float)a.hh[0]; a1 += (float)a.hh[1];
                a2 += (float)a.hh[2]; a3 += (float)a.hh[3];
            }
            float sc = gl[r];
            float4 xv = *(const float4*)&x[g];
            float4 o;
            o.x = a0 * sc + xv.x; o.y = a1 * sc + xv.y;
            o.z = a2 * sc + xv.z; o.w = a3 * sc + xv.w;
            *(float4*)&out[g] = o;
        }
    }
}

// ---------------------------------------------------------------------------
extern "C" void kernel_launch(void* const* d_in, const int* in_sizes, int n_in,
                              void* d_out, int out_size, void* d_ws, size_t ws_size,
                              hipStream_t stream) {
    const float* x     = (const float*)d_in[0];
    const float* Wb    = (const float*)d_in[1];
    const float* Wc    = (const float*)d_in[2];
    const float* Wd    = (const float*)d_in[3];
    const float* gamma = (const float*)d_in[4];
    float*       out   = (float*)d_out;

    // ws: qswz .5M | kswz .5M | vswz 4M | Opart 4x4M bf16 | lws 256K | cnt 2K
    __bf16* qswz  = (__bf16*)d_ws;
    __bf16* kswz  = qswz + (size_t)NROWS * NCQ;
    __bf16* vswz  = kswz + (size_t)NROWS * NCQ;
    __bf16* Opart = vswz + (size_t)NB * NC * NN;
    float*  lws   = (float*)(Opart + (size_t)NSLICE * NROWS * NC);
    int*    cnt   = (int*)(lws + (size_t)NSLICE * NROWS);

    proj_kernel<<<NROWS / 32, 256, 0, stream>>>(x, Wb, Wc, Wd,
                                                qswz, kswz, vswz, cnt);
    attn_kernel<<<NB * 128 * 2, 256, 0, stream>>>(qswz, kswz, vswz, Opart, lws,
                                                  cnt, x, gamma, out);
}

// Round 14
// 107.797 us; speedup vs baseline: 2.9619x; 2.9619x over previous
//
#include <hip/hip_runtime.h>

// Problem constants: B=4, h=w=z=16 -> N=4096, C=128, Cq=16
#define NB     4
#define NN     4096
#define NC     128
#define NCQ    16
#define NROWS  (NB * NN)      // 16384
#define NSLICE 8
#define NIT    (NN / 64 / NSLICE)   // 8 iterations of 64 keys per slice

typedef __attribute__((ext_vector_type(8)))  __bf16 bf16x8;
typedef __attribute__((ext_vector_type(4)))  float  f32x4;
typedef __attribute__((ext_vector_type(16))) float  f32x16;

#define MFMA16(a,b,c) __builtin_amdgcn_mfma_f32_16x16x32_bf16((a),(b),(c),0,0,0)
#define MFMA32(a,b,c) __builtin_amdgcn_mfma_f32_32x32x16_bf16((a),(b),(c),0,0,0)
#define LOG2E 1.44269504f
// Schraudolph bias for direct-to-bf16 exp2: bits(bf16(2^s)) ~= 128*s + 16248.66
#define SCH_BIAS 16248.66f

__device__ __forceinline__ f32x16 zero16() {
    f32x16 v;
    #pragma unroll
    for (int i = 0; i < 16; ++i) v[i] = 0.f;
    return v;
}

// Swizzled fragment layouts (lane = lh*32 + l31):
//  qswz: [batch][qb32][lane][8]  elem j = (LOG2E * Q)[32*qb32 + l31][ch = 8*lh + j]
//  kswz: [batch][kb32][lane][8]  elem j = K[32*kb32 + l31][ch = 8*lh + j]
//  vswz: [batch][kb16][cg][lane][8]
//        elem j = V^T[ch = 32*cg + l31][key = 16*kb16 + 4*lh + (j&3) + 8*(j>>2)]

// ---------------------------------------------------------------------------
// Kernel 1: projections via MFMA; W^T staged in-block directly from fp32
// Wb/Wc/Wd (wtrans folded in — R13-verified staging, R12-verified MFMA path).
// ---------------------------------------------------------------------------
__global__ __launch_bounds__(256) void proj_kernel(
    const float* __restrict__ x,  const float* __restrict__ Wb,
    const float* __restrict__ Wc, const float* __restrict__ Wd,
    __bf16* __restrict__ qswz, __bf16* __restrict__ kswz,
    __bf16* __restrict__ vswz)
{
    __shared__ __align__(16) __bf16 xsh[32 * 136];   // [row][136]
    __shared__ __align__(16) __bf16 wt [160 * 136];  // [outcol][136]
    __shared__ __align__(16) float  osb[4][16 * 17]; // per-wave transpose buffer

    const int  t    = threadIdx.x;
    const int  lane = t & 63, w = t >> 6;
    const int  q16  = lane & 15, quad = lane >> 4;
    const long row0 = (long)blockIdx.x * 32;
    const int  batch = (int)(row0 >> 12);
    const int  nloc  = (int)(row0 & 4095);
    const int  rh   = w & 1;
    const int  og   = (w >> 1) * 5;

    // ---- stage X tile (fp32 -> bf16), [32][128] -> xsh stride 136 ----
    #pragma unroll
    for (int i = 0; i < 4; ++i) {
        int idx = t + 256 * i;           // < 1024
        int r = idx >> 5, c4 = (idx & 31) * 4;
        float4 xv = *(const float4*)&x[(row0 + r) * NC + c4];
        union { __bf16 h[4]; uint2 u; } cv;
        cv.h[0] = (__bf16)xv.x; cv.h[1] = (__bf16)xv.y;
        cv.h[2] = (__bf16)xv.z; cv.h[3] = (__bf16)xv.w;
        *(uint2*)&xsh[r * 136 + c4] = cv.u;
    }
    // ---- stage W^T from fp32 globals: wt[oc][ch] ----
    #pragma unroll
    for (int i = 0; i < 2; ++i) {        // Wb: 512 float4 -> oc 0..15
        int idx = t + 256 * i;
        int ch = idx >> 2, o4 = (idx & 3) * 4;
        float4 v = *(const float4*)&Wb[ch * 16 + o4];
        wt[(o4 + 0) * 136 + ch] = (__bf16)v.x;
        wt[(o4 + 1) * 136 + ch] = (__bf16)v.y;
        wt[(o4 + 2) * 136 + ch] = (__bf16)v.z;
        wt[(o4 + 3) * 136 + ch] = (__bf16)v.w;
    }
    #pragma unroll
    for (int i = 0; i < 2; ++i) {        // Wc: 512 float4 -> oc 16..31
        int idx = t + 256 * i;
        int ch = idx >> 2, o4 = (idx & 3) * 4;
        float4 v = *(const float4*)&Wc[ch * 16 + o4];
        wt[(16 + o4 + 0) * 136 + ch] = (__bf16)v.x;
        wt[(16 + o4 + 1) * 136 + ch] = (__bf16)v.y;
        wt[(16 + o4 + 2) * 136 + ch] = (__bf16)v.z;
        wt[(16 + o4 + 3) * 136 + ch] = (__bf16)v.w;
    }
    #pragma unroll
    for (int i = 0; i < 16; ++i) {       // Wd: 4096 float4 -> oc 32..159
        int idx = t + 256 * i;
        int ch = idx >> 5, o4 = (idx & 31) * 4;
        float4 v = *(const float4*)&Wd[ch * 128 + o4];
        wt[(32 + o4 + 0) * 136 + ch] = (__bf16)v.x;
        wt[(32 + o4 + 1) * 136 + ch] = (__bf16)v.y;
        wt[(32 + o4 + 2) * 136 + ch] = (__bf16)v.z;
        wt[(32 + o4 + 3) * 136 + ch] = (__bf16)v.w;
    }
    __syncthreads();

    bf16x8 xf[4];
    #pragma unroll
    for (int kc = 0; kc < 4; ++kc)
        xf[kc] = *(const bf16x8*)&xsh[(rh * 16 + q16) * 136 + kc * 32 + quad * 8];

    float* osw = osb[w];
    #pragma unroll
    for (int oc_t = 0; oc_t < 5; ++oc_t) {
        const int oset = og + oc_t;
        f32x4 acc = {0.f, 0.f, 0.f, 0.f};
        #pragma unroll
        for (int kc = 0; kc < 4; ++kc) {
            bf16x8 wf = *(const bf16x8*)&wt[(oset * 16 + q16) * 136 + kc * 32 + quad * 8];
            acc = MFMA16(wf, xf[kc], acc);   // D'[oc][row]
        }
        #pragma unroll
        for (int r = 0; r < 4; ++r)
            osw[(quad * 4 + r) * 17 + q16] = acc[r];   // osb[oc16][xrow16]

        if (oset >= 2) {
            int ch_l = lane & 15, lh_t = (lane >> 4) & 1, jh = lane >> 5;
            union { __bf16 h[4]; uint2 u; } cv;
            #pragma unroll
            for (int u2 = 0; u2 < 4; ++u2)
                cv.h[u2] = (__bf16)osw[ch_l * 17 + 8 * jh + 4 * lh_t + u2];
            int kb16 = (nloc >> 4) + rh;
            int cg   = (oset - 2) >> 1;
            int l31v = ((oset - 2) & 1) * 16 + ch_l;
            size_t off = ((((size_t)batch * 256 + kb16) * 4 + cg) << 9)
                       + (size_t)(lh_t * 32 + l31v) * 8 + jh * 4;
            *(uint2*)&vswz[off] = cv.u;
        } else if (lane < 32) {
            int xr = lane & 15, lh_t = lane >> 4;
            const float qsc = (oset == 0) ? LOG2E : 1.f;  // fold log2e into Q
            union { __bf16 h[8]; uint4 u; } cv;
            #pragma unroll
            for (int j = 0; j < 8; ++j)
                cv.h[j] = (__bf16)(osw[(8 * lh_t + j) * 17 + xr] * qsc);
            size_t off = ((((size_t)batch * 128 + (nloc >> 5)) * 64)
                       + (size_t)(lh_t * 32 + rh * 16 + xr)) * 8;
            __bf16* dst = (oset == 0) ? qswz : kswz;
            *(uint4*)&dst[off] = cv.u;
        }
    }
}

// ---------------------------------------------------------------------------
// Kernel 2: flash attention — R12 core (frozen), split-K widened to x8 for
// occupancy (grid 2048 = 8 blocks/CU offered; (256,4) cap=128 VGPR, measured
// 84 so no spill). XCD swizzle: bid&7 -> (batch, slice-low); slice-high from
// upper grid bits => each XCD sees one batch, half of K/V (~0.6 MB, L2-res).
// Plain bf16 partial stores; NO fences, NO cross-block rendezvous (R13 lesson).
// ---------------------------------------------------------------------------
__global__ __launch_bounds__(256, 4) void attn_kernel(
    const __bf16* __restrict__ qswz, const __bf16* __restrict__ kswz,
    const __bf16* __restrict__ vswz, __bf16* __restrict__ Opart,
    float* __restrict__ lws)
{
    const int t    = threadIdx.x;
    const int lane = t & 63, w = t >> 6;
    const int l31 = lane & 31, lh = lane >> 5;
    const int bid   = blockIdx.x;
    const int xcd   = bid & 7;
    const int batch = xcd >> 1;              // constant per XCD
    const int spL   = xcd & 1;               // slice low bit, constant per XCD
    const int idx   = bid >> 3;              // 0..255
    const int qb32  = idx & 127;
    const int spH   = idx >> 7;              // 0..1
    const int h     = w & 1;                 // channel half
    const int slice = ((spH << 1) | spL) * 2 + (w >> 1);   // 0..7
    const int ks0   = slice * (64 * NIT);

    // Q B-frag, fixed: n = q = 32*qb32 + l31, k = ch = 8*lh + j
    const bf16x8 qf = *(const bf16x8*)
        &qswz[(((size_t)batch * 128 + qb32) * 64 + lane) * 8];

    const __bf16* kptr = kswz + ((size_t)batch * 128 + (ks0 >> 5)) * 512 + lane * 8;
    const __bf16* vptr = vswz + ((size_t)batch * 256 + (ks0 >> 4)) * 2048
                       + h * 1024 + lane * 8;

    // ones B-fragment (bf16 1.0 pairs) for the l-summing MFMA
    union { uint32_t u[4]; bf16x8 f; } onesu;
    #pragma unroll
    for (int i = 0; i < 4; ++i) onesu.u[i] = 0x3F803F80u;
    const bf16x8 ones = onesu.f;

    f32x16 O0 = zero16(), O1 = zero16(), Ol = zero16();

    bf16x8 kf0 = *(const bf16x8*)(kptr);
    bf16x8 kf1 = *(const bf16x8*)(kptr + 512);
    bf16x8 va[8], vb[8];
    #pragma unroll
    for (int b = 0; b < 4; ++b) {           // iter-0 V frags (ct = 0,1)
        va[2*b]     = *(const bf16x8*)(vptr + (size_t)(b * 4)     * 512);
        va[2*b + 1] = *(const bf16x8*)(vptr + (size_t)(b * 4 + 1) * 512);
    }
    f32x16 S0 = MFMA32(kf0, qf, zero16());
    f32x16 S1 = MFMA32(kf1, qf, zero16());

#define ATTN_BODY(IT, CUR, NXT)                                               \
    {                                                                         \
        const int itn = ((IT) + 1 < NIT) ? (IT) + 1 : (IT);                   \
        kf0 = *(const bf16x8*)(kptr + (size_t)itn * 1024);                    \
        kf1 = *(const bf16x8*)(kptr + (size_t)itn * 1024 + 512);              \
        _Pragma("unroll")                                                     \
        for (int b = 0; b < 4; ++b) {                                         \
            NXT[2*b]     = *(const bf16x8*)(vptr + (size_t)((itn*4+b)*4)*512);\
            NXT[2*b + 1] = *(const bf16x8*)(vptr + (size_t)((itn*4+b)*4+1)*512);\
        }                                                                     \
        union { uint32_t u32[16]; bf16x8 f[4]; } pk;                          \
        _Pragma("unroll")                                                     \
        for (int i = 0; i < 8; ++i) {                                         \
            int e0 = (int)fmaf(S0[2*i],   128.f, SCH_BIAS);                   \
            int e1 = (int)fmaf(S0[2*i+1], 128.f, SCH_BIAS);                   \
            int e2 = (int)fmaf(S1[2*i],   128.f, SCH_BIAS);                   \
            int e3 = (int)fmaf(S1[2*i+1], 128.f, SCH_BIAS);                   \
            pk.u32[i]     = (uint32_t)((e1 << 16) | e0);                      \
            pk.u32[8 + i] = (uint32_t)((e3 << 16) | e2);                      \
        }                                                                     \
        _Pragma("unroll")                                                     \
        for (int b = 0; b < 4; ++b) {                                         \
            O0 = MFMA32(pk.f[b], CUR[2*b],     O0);                           \
            O1 = MFMA32(pk.f[b], CUR[2*b + 1], O1);                           \
            Ol = MFMA32(pk.f[b], ones,         Ol);                           \
        }                                                                     \
        S0 = MFMA32(kf0, qf, zero16());                                       \
        S1 = MFMA32(kf1, qf, zero16());                                       \
    }

    for (int it = 0; it < NIT; it += 2) {
        ATTN_BODY(it,     va, vb);
        ATTN_BODY(it + 1, vb, va);
    }
#undef ATTN_BODY

    const long base = (long)batch * NN;

    // ---- l: Ol reg r holds sum over ALL this slice's keys for q(r), any col.
    if (h == 0 && l31 == 0) {
        #pragma unroll
        for (int r = 0; r < 16; ++r) {
            int q = qb32 * 32 + (r & 3) + 8 * (r >> 2) + 4 * lh;
            lws[(size_t)slice * NROWS + base + q] = Ol[r];
        }
    }

    // ---- O partial -> Opart[slice][row][ch] bf16 (col = ch = 64h+32ct+l31) --
    #pragma unroll
    for (int ct = 0; ct < 2; ++ct) {
        f32x16 Ov = ct ? O1 : O0;
        #pragma unroll
        for (int r = 0; r < 16; ++r) {
            int q = qb32 * 32 + (r & 3) + 8 * (r >> 2) + 4 * lh;
            Opart[((size_t)slice * NROWS + base + q) * NC + 64 * h + 32 * ct + l31]
                = (__bf16)Ov[r];
        }
    }
}

// ---------------------------------------------------------------------------
// Kernel 3: combine 8 slice partials + epilogue: out = gamma*(SumO/Suml)+x.
// ---------------------------------------------------------------------------
__global__ __launch_bounds__(256) void combine_kernel(
    const __bf16* __restrict__ Op, const float* __restrict__ lws,
    const float* __restrict__ x, const float* __restrict__ gamma,
    float* __restrict__ out)
{
    __shared__ float gl[32];
    const int  t    = threadIdx.x;
    const long row0 = (long)blockIdx.x * 32;
    if (t < 32) {
        float l = 0.f;
        #pragma unroll
        for (int s = 0; s < NSLICE; ++s) l += lws[(size_t)s * NROWS + row0 + t];
        gl[t] = gamma[0] / l;
    }
    __syncthreads();
    const size_t s1 = (size_t)NROWS * NC;
    #pragma unroll
    for (int i = 0; i < 4; ++i) {
        int idx = t + 256 * i;                 // < 1024 float4 groups
        int r = idx >> 5, c4 = (idx & 31) * 4;
        size_t g = (size_t)(row0 + r) * NC + c4;
        float a0 = 0.f, a1 = 0.f, a2 = 0.f, a3 = 0.f;
        #pragma unroll
        for (int s = 0; s < NSLICE; ++s) {
            union { __bf16 h[4]; uint2 u; } a;
            a.u = *(const uint2*)&Op[s1 * s + g];
            a0 += (float)a.h[0]; a1 += (float)a.h[1];
            a2 += (float)a.h[2]; a3 += (float)a.h[3];
        }
        float sc = gl[r];
        float4 xv = *(const float4*)&x[g];
        float4 o;
        o.x = a0 * sc + xv.x; o.y = a1 * sc + xv.y;
        o.z = a2 * sc + xv.z; o.w = a3 * sc + xv.w;
        *(float4*)&out[g] = o;
    }
}

// ---------------------------------------------------------------------------
extern "C" void kernel_launch(void* const* d_in, const int* in_sizes, int n_in,
                              void* d_out, int out_size, void* d_ws, size_t ws_size,
                              hipStream_t stream) {
    const float* x     = (const float*)d_in[0];
    const float* Wb    = (const float*)d_in[1];
    const float* Wc    = (const float*)d_in[2];
    const float* Wd    = (const float*)d_in[3];
    const float* gamma = (const float*)d_in[4];
    float*       out   = (float*)d_out;

    // ws: qswz .5M | kswz .5M | vswz 4M | Opart 8x4M bf16 | lws 512K  (~37.5 MB)
    __bf16* qswz  = (__bf16*)d_ws;
    __bf16* kswz  = qswz + (size_t)NROWS * NCQ;
    __bf16* vswz  = kswz + (size_t)NROWS * NCQ;
    __bf16* Opart = vswz + (size_t)NB * NC * NN;
    float*  lws   = (float*)(Opart + (size_t)NSLICE * NROWS * NC);

    proj_kernel   <<<NROWS / 32, 256, 0, stream>>>(x, Wb, Wc, Wd, qswz, kswz, vswz);
    attn_kernel   <<<NB * 128 * 2, 256, 0, stream>>>(qswz, kswz, vswz, Opart, lws);
    combine_kernel<<<NROWS / 32, 256, 0, stream>>>(Opart, lws, x, gamma, out);
}